// Round 3
// baseline (1168.430 us; speedup 1.0000x reference)
//
#include <hip/hip_runtime.h>
#include <hip/hip_bf16.h>
#include <math.h>

// WReN forward (loss, acc) — bf16 MFMA.
// Round 6: round-2's drain-0-per-tile schedule regressed both 256^2 GEMMs
// (T4 anti-pattern; 1 block/CU => no TLP to hide the drain). This round
// restores the round-1 counted-vmcnt 8-phase skeleton and keeps round-2's
// verified fusions:
//  - AMODE 1: A built on the fly as relu(U[p&7]+V[p>>3]) (H1 never exists)
//  - CMODE 0: LDS-routed 16B-coalesced store epilogue
//  - B-fragment register reuse (24 vs 32 ds_read_b128 per wave per K-tile),
//    which also frees the B LDS region after P2 (enables early staging).
// Ledger per iteration (tiles t,t+1; stage t+2 AND t+3):
//  t+2 (buf0): UV@P1,P2 / SB h0@P3 / {W|SA}@P4 / SB h1@P5 -> gate@P8
//              (counted: AMODE0 vmcnt(8), AMODE1 vmcnt(4)+lgkm0)
//  t+3 (buf1): UV@P5,P6 / SB h0@P7 / SB h1+{W|SA}@P8 -> gate@next-P4
//              (counted: AMODE0 vmcnt(6), AMODE1 vmcnt(2)+lgkm0)
// Region-safety: buf A free after P3/P7 (LDA4(.,4) consumed pre-barrier);
// buf B free after P2/P6 (B-reuse). All stages land at/after those points.

typedef __bf16 bf16;
typedef __bf16 v8bf __attribute__((ext_vector_type(8)));
typedef float  v4f  __attribute__((ext_vector_type(4)));
typedef unsigned long long u64;

#define GAS(p) ((const __attribute__((address_space(1))) void*)(p))
#define LAS(p) ((__attribute__((address_space(3))) void*)(p))

// ---------------------------------------------------------------------------
// OLD 128^2 kernel (unchanged): used for emb, U, V, HF.
__global__ __launch_bounds__(256) void gemm_bf16(
    const bf16* __restrict__ A, int lda,
    const bf16* __restrict__ Bt, int ldb,
    bf16* __restrict__ C, int ldc,
    int Mt, int Nt,
    int Nreal, int Nstore, int K,
    const float* __restrict__ bias,
    const float* __restrict__ tagW, int tag_ld,
    int relu, int mode)
{
    __shared__ bf16 As[128 * 32];
    __shared__ bf16 Bs[128 * 32];
    __shared__ bf16 Epi[64 * 132];

    const int L    = blockIdx.x;
    const int xcd  = L & 7;
    const int idx  = L >> 3;
    const int mlee = idx / Nt;
    const int n    = idx - mlee * Nt;
    const int m    = xcd * (Mt >> 3) + mlee;
    const int row0 = m * 128;
    const int col0 = n * 128;

    const int tid  = threadIdx.x;
    const int wv   = tid >> 6;
    const int lane = tid & 63;
    const int quad = lane >> 4;
    const int l15  = lane & 15;
    const int wm0  = (wv >> 1) * 64;
    const int wn0  = (wv & 1) * 64;

    v4f acc[4][4] = {};

    const int srow  = wv * 32 + (lane >> 2);
    const int skoff = (lane & 3) * 8;
    const bf16* ga = A  + (size_t)(row0 + srow) * lda + skoff;
    const bf16* gb = Bt + (size_t)(col0 + srow) * ldb + skoff;
    bf16* laA = &As[(wv * 32) * 32];
    bf16* laB = &Bs[(wv * 32) * 32];

    for (int k0 = 0; k0 < K; k0 += 32) {
        __builtin_amdgcn_global_load_lds(GAS(ga),                    LAS(laA),           16, 0, 0);
        __builtin_amdgcn_global_load_lds(GAS(ga + (size_t)16 * lda), LAS(laA + 16 * 32), 16, 0, 0);
        __builtin_amdgcn_global_load_lds(GAS(gb),                    LAS(laB),           16, 0, 0);
        __builtin_amdgcn_global_load_lds(GAS(gb + (size_t)16 * ldb), LAS(laB + 16 * 32), 16, 0, 0);
        ga += 32; gb += 32;
        __syncthreads();

        v8bf af[4], bfq[4];
        #pragma unroll
        for (int i = 0; i < 4; ++i)
            af[i] = *(const v8bf*)&As[(wm0 + i * 16 + l15) * 32 + quad * 8];
        #pragma unroll
        for (int j = 0; j < 4; ++j)
            bfq[j] = *(const v8bf*)&Bs[(wn0 + j * 16 + l15) * 32 + quad * 8];
        #pragma unroll
        for (int i = 0; i < 4; ++i)
            #pragma unroll
            for (int j = 0; j < 4; ++j)
                acc[i][j] = __builtin_amdgcn_mfma_f32_16x16x32_bf16(af[i], bfq[j], acc[i][j], 0, 0, 0);
        __syncthreads();
    }

    float bcol[4];
    #pragma unroll
    for (int j = 0; j < 4; ++j) {
        int col = col0 + wn0 + j * 16 + l15;
        bcol[j] = (col < Nreal && bias) ? bias[col] : 0.f;
    }

    float s_ctx = 0.f;

    #pragma unroll
    for (int pass = 0; pass < 2; ++pass) {
        if (wm0 == pass * 64) {
            #pragma unroll
            for (int i = 0; i < 4; ++i) {
                #pragma unroll
                for (int j = 0; j < 4; ++j) {
                    #pragma unroll
                    for (int r = 0; r < 4; ++r) {
                        int lrow = i * 16 + quad * 4 + r;
                        int lcol = wn0 + j * 16 + l15;
                        int col  = col0 + lcol;
                        float v = 0.f;
                        if (col < Nreal) {
                            v = acc[i][j][r] + bcol[j];
                            if (tagW) {
                                int row = row0 + pass * 64 + lrow;
                                int tp = row & 15; if (tp > 8) tp = 8;
                                v += tagW[(size_t)tp * tag_ld + col];
                            }
                            if (relu) v = fmaxf(v, 0.f);
                        }
                        Epi[lrow * 132 + lcol] = (bf16)v;
                    }
                }
            }
        }
        __syncthreads();

        if (mode == 0) {
            int lrow = tid >> 2;
            int cg   = (tid & 3) * 32;
            int grow = row0 + pass * 64 + lrow;
            #pragma unroll
            for (int k = 0; k < 4; ++k) {
                int c = cg + k * 8;
                int gcol = col0 + c;
                if (gcol < Nstore) {
                    u64 q0 = *(const u64*)&Epi[lrow * 132 + c];
                    u64 q1 = *(const u64*)&Epi[lrow * 132 + c + 4];
                    uint4 st;
                    st.x = (unsigned)q0; st.y = (unsigned)(q0 >> 32);
                    st.z = (unsigned)q1; st.w = (unsigned)(q1 >> 32);
                    *(uint4*)&C[(size_t)grow * ldc + gcol] = st;
                }
            }
        } else {
            if (tid < 128) {
                int col = tid;
                if (pass == 0) {
                    float s = 0.f;
                    for (int r = 0; r < 64; ++r) s += (float)Epi[r * 132 + col];
                    s_ctx = s;
                } else {
                    float sA[8] = {};
                    for (int r = 0; r < 64; ++r) sA[r >> 3] += (float)Epi[r * 132 + col];
                    int gcol = col0 + col;
                    if (gcol < Nstore) {
                        #pragma unroll
                        for (int a = 0; a < 8; ++a)
                            C[(size_t)(m * 8 + a) * ldc + gcol] = (bf16)(s_ctx + sA[a]);
                    }
                }
            }
        }
        __syncthreads();
    }
}

// ---------------------------------------------------------------------------
// 256x256 tile, BK=64, 8 waves (2M x 4N), dbuf 128KiB LDS, counted 8-phase.
template<int AMODE, int CMODE>
__global__ __launch_bounds__(512, 2) void gemm256(
    const bf16* __restrict__ A, int lda,
    const bf16* __restrict__ U, const bf16* __restrict__ V, int lduv,
    const bf16* __restrict__ Bt, int ldb,
    bf16* __restrict__ C, int ldc,
    int Mt, int Nt, int Nreal, int Nstore, int K,
    const float* __restrict__ bias)
{
    extern __shared__ char smem[];   // [A: 2buf x 32KB][B: 2buf x 32KB]

    const int NTK = K >> 6;

    const int L    = blockIdx.x;
    const int xcd  = L & 7;
    const int idx  = L >> 3;
    const int mlee = idx / Nt;
    const int n    = idx - mlee * Nt;
    const int m    = xcd * (Mt >> 3) + mlee;
    const int row0 = m * 256;
    const int col0 = n * 256;

    const int tid  = threadIdx.x;
    const int wv   = tid >> 6;
    const int lane = tid & 63;
    const int wr   = wv >> 2;          // 2 M-halves
    const int wc   = wv & 3;           // 4 N-quarters
    const int l15  = lane & 15;
    const int quad = lane >> 4;
    const int s7   = l15 & 7;
    const int slot0 = ((0 + quad) ^ s7) << 4;   // kk=0 16B slot (swizzled)
    const int slot1 = ((4 + quad) ^ s7) << 4;   // kk=1

    char* const aRd = smem + wr * 16384;                                 // + bo
    char* const bRd = smem + 65536 + (wc >> 1) * 16384 + (wc & 1) * 8192;

    // staging geometry: thread t covers half-tile row srow=t>>3 (and +64),
    // logical 16B slot sl=t&7; swizzle: phys = sl ^ (srow&7).
    const int srow = tid >> 3;
    const int sl   = tid & 7;
    const int gce  = (sl ^ (srow & 7)) * 8;     // pre-swizzled source col
    const bf16* const Ab = (AMODE == 0) ? A + (size_t)(row0 + srow) * lda + gce
                                        : (const bf16*)nullptr;
    const bf16* const Bb = Bt + (size_t)(col0 + srow) * ldb + gce;

#define STAGE_A(kt, bo, h) { \
    const bf16* s_ = Ab + (size_t)((h) * 128) * lda + (kt) * 64; \
    char* d_ = smem + (bo) + (h) * 16384 + wv * 1024; \
    __builtin_amdgcn_global_load_lds(GAS(s_),                    LAS(d_),        16, 0, 0); \
    __builtin_amdgcn_global_load_lds(GAS(s_ + (size_t)64 * lda), LAS(d_ + 8192), 16, 0, 0); }
#define STAGE_B(kt, bo, h) { \
    const bf16* s_ = Bb + (size_t)((h) * 128) * ldb + (kt) * 64; \
    char* d_ = smem + 65536 + (bo) + (h) * 16384 + wv * 1024; \
    __builtin_amdgcn_global_load_lds(GAS(s_),                    LAS(d_),        16, 0, 0); \
    __builtin_amdgcn_global_load_lds(GAS(s_ + (size_t)64 * ldb), LAS(d_ + 8192), 16, 0, 0); }

#define LDA4(bo, qmB) \
    _Pragma("unroll") \
    for (int i_ = 0; i_ < 4; ++i_) { \
        afr[i_][0] = *(const v8bf*)(aRd + (bo) + (((qmB) + i_) * 16 + l15) * 128 + slot0); \
        afr[i_][1] = *(const v8bf*)(aRd + (bo) + (((qmB) + i_) * 16 + l15) * 128 + slot1); \
    }
#define LDB2(bo, nfB) \
    _Pragma("unroll") \
    for (int j_ = 0; j_ < 2; ++j_) { \
        bfr[(nfB) + j_][0] = *(const v8bf*)(bRd + (bo) + (((nfB) + j_) * 16 + l15) * 128 + slot0); \
        bfr[(nfB) + j_][1] = *(const v8bf*)(bRd + (bo) + (((nfB) + j_) * 16 + l15) * 128 + slot1); \
    }
#define MM8(qmA, nfB) \
    _Pragma("unroll") \
    for (int i_ = 0; i_ < 4; ++i_) \
        _Pragma("unroll") \
        for (int j_ = 0; j_ < 2; ++j_) { \
            acc[(qmA) + i_][(nfB) + j_] = __builtin_amdgcn_mfma_f32_16x16x32_bf16(afr[i_][0], bfr[(nfB) + j_][0], acc[(qmA) + i_][(nfB) + j_], 0, 0, 0); \
            acc[(qmA) + i_][(nfB) + j_] = __builtin_amdgcn_mfma_f32_16x16x32_bf16(afr[i_][1], bfr[(nfB) + j_][1], acc[(qmA) + i_][(nfB) + j_], 0, 0, 0); \
        }
#define UVLOAD(uu, vv, h, t1) { \
    uu[0] = *(const v8bf*)(U + uo[h][0] + (t1) * 64); \
    vv[0] = *(const v8bf*)(V + vo[h][0] + (t1) * 64); \
    uu[1] = *(const v8bf*)(U + uo[h][1] + (t1) * 64); \
    vv[1] = *(const v8bf*)(V + vo[h][1] + (t1) * 64); }
#define WRITEA(uu, vv, bo, h) { \
    _Pragma("unroll") \
    for (int q_ = 0; q_ < 2; ++q_) { \
        v8bf o_; \
        _Pragma("unroll") \
        for (int e_ = 0; e_ < 8; ++e_) \
            o_[e_] = (bf16)fmaxf((float)uu[q_][e_] + (float)vv[q_][e_], 0.f); \
        *(v8bf*)(smem + (bo) + (h) * 16384 + (q_ * 64 + srow) * 128 + ((sl ^ (srow & 7)) << 4)) = o_; \
    } }
#define BAR()   asm volatile("s_barrier" ::: "memory")
#define PRIO1() __builtin_amdgcn_s_setprio(1)
#define PRIO0() __builtin_amdgcn_s_setprio(0)

    v4f acc[8][4] = {};
    v8bf afr[4][2], bfr[4][2];
    v8bf u0[2], v0[2], u1[2], v1[2];
    int uo[2][2], vo[2][2];

    if constexpr (AMODE == 1) {
        #pragma unroll
        for (int h = 0; h < 2; ++h)
            #pragma unroll
            for (int q = 0; q < 2; ++q) {
                int gr = row0 + h * 128 + q * 64 + srow;
                int bb = gr >> 7, p = gr & 127;
                uo[h][q] = (bb * 16 + (p & 7)) * lduv + sl * 8;
                vo[h][q] = (bb * 16 + (p >> 3)) * lduv + sl * 8;
            }
    }

    // ---- prologue: tiles 0 (buf0) and 1 (buf1) fully staged ----
    if constexpr (AMODE == 0) {
        STAGE_A(0, 0, 0); STAGE_A(0, 0, 1);
    } else {
        UVLOAD(u0, v0, 0, 0); UVLOAD(u1, v1, 1, 0);
        WRITEA(u0, v0, 0, 0); WRITEA(u1, v1, 0, 1);
    }
    STAGE_B(0, 0, 0); STAGE_B(0, 0, 1);
    if (NTK > 1) {
        if constexpr (AMODE == 0) {
            STAGE_A(1, 32768, 0); STAGE_A(1, 32768, 1);
        } else {
            UVLOAD(u0, v0, 0, 1); UVLOAD(u1, v1, 1, 1);
            WRITEA(u0, v0, 32768, 0); WRITEA(u1, v1, 32768, 1);
        }
        STAGE_B(1, 32768, 0); STAGE_B(1, 32768, 1);
    }
    asm volatile("s_waitcnt vmcnt(0) lgkmcnt(0)" ::: "memory");
    BAR();

    int t = 0;
    for (; t + 1 < NTK; t += 2) {
        const bool h2 = (t + 2 < NTK);
        const bool h3 = (t + 3 < NTK);
        // -------- tile t (buf0) --------
        // P1
        LDA4(0, 0); LDB2(0, 0);
        if constexpr (AMODE == 1) { if (h2) UVLOAD(u0, v0, 0, t + 2); }
        BAR(); PRIO1(); MM8(0, 0); PRIO0(); BAR();
        // P2
        LDB2(0, 2);
        if constexpr (AMODE == 1) { if (h2) UVLOAD(u1, v1, 1, t + 2); }
        BAR(); PRIO1(); MM8(0, 2); PRIO0(); BAR();
        // P3  (buf0 B region free after P2)
        LDA4(0, 4);
        if (h2) STAGE_B(t + 2, 0, 0);
        BAR(); PRIO1(); MM8(4, 0); PRIO0(); BAR();
        // P4  (buf0 A region free after P3); gate: tile t+1 must be complete
        if (h2) {
            if constexpr (AMODE == 1) { WRITEA(u0, v0, 0, 0); WRITEA(u1, v1, 0, 1); }
            else                      { STAGE_A(t + 2, 0, 0); STAGE_A(t + 2, 0, 1); }
        }
        BAR(); PRIO1(); MM8(4, 2); PRIO0();
        if constexpr (AMODE == 0) {
            if (h2) asm volatile("s_waitcnt vmcnt(6)" ::: "memory");
            else    asm volatile("s_waitcnt vmcnt(0)" ::: "memory");
        } else {
            if (h2) asm volatile("s_waitcnt vmcnt(2) lgkmcnt(0)" ::: "memory");
            else    asm volatile("s_waitcnt vmcnt(0) lgkmcnt(0)" ::: "memory");
        }
        BAR();
        // -------- tile t+1 (buf1) --------
        // P5
        LDA4(32768, 0); LDB2(32768, 0);
        if (h2) STAGE_B(t + 2, 0, 1);
        if constexpr (AMODE == 1) { if (h3) UVLOAD(u0, v0, 0, t + 3); }
        BAR(); PRIO1(); MM8(0, 0); PRIO0(); BAR();
        // P6
        LDB2(32768, 2);
        if constexpr (AMODE == 1) { if (h3) UVLOAD(u1, v1, 1, t + 3); }
        BAR(); PRIO1(); MM8(0, 2); PRIO0(); BAR();
        // P7  (buf1 B region free after P6)
        LDA4(32768, 4);
        if (h3) STAGE_B(t + 3, 32768, 0);
        BAR(); PRIO1(); MM8(4, 0); PRIO0(); BAR();
        // P8  (buf1 A region free after P7); gate: tile t+2 must be complete
        if (h3) {
            STAGE_B(t + 3, 32768, 1);
            if constexpr (AMODE == 1) { WRITEA(u0, v0, 32768, 0); WRITEA(u1, v1, 32768, 1); }
            else                      { STAGE_A(t + 3, 32768, 0); STAGE_A(t + 3, 32768, 1); }
        }
        BAR(); PRIO1(); MM8(4, 2); PRIO0();
        if constexpr (AMODE == 0) {
            if (h3) asm volatile("s_waitcnt vmcnt(8)" ::: "memory");
            else    asm volatile("s_waitcnt vmcnt(0)" ::: "memory");
        } else {
            if (h3) asm volatile("s_waitcnt vmcnt(4) lgkmcnt(0)" ::: "memory");
            else    asm volatile("s_waitcnt vmcnt(0) lgkmcnt(0)" ::: "memory");
        }
        BAR();
    }
    if (t < NTK) {  // peeled odd tile (buf0), no staging
        LDA4(0, 0); LDB2(0, 0);
        BAR(); PRIO1(); MM8(0, 0); PRIO0(); BAR();
        LDB2(0, 2);
        BAR(); PRIO1(); MM8(0, 2); PRIO0(); BAR();
        LDA4(0, 4);
        BAR(); PRIO1(); MM8(4, 0); PRIO0(); BAR();
        PRIO1(); MM8(4, 2); PRIO0();
    }

    // ---- epilogue ----
    if constexpr (CMODE == 0) {
        // LDS re-stage (bank-swizzled), 16B coalesced global stores.
        __syncthreads();
        bf16* epi = (bf16*)(smem + wv * 16384);   // this wave's 128x64 tile
        #pragma unroll
        for (int j = 0; j < 4; ++j) {
            int col = col0 + wc * 64 + j * 16 + l15;
            bool real = col < Nreal;
            float bc = (real && bias) ? bias[col] : 0.f;
            #pragma unroll
            for (int i = 0; i < 8; ++i) {
                #pragma unroll
                for (int r = 0; r < 4; ++r) {
                    int lrow = i * 16 + quad * 4 + r;
                    float v = real ? fmaxf(acc[i][j][r] + bc, 0.f) : 0.f;
                    int slt = (j * 2 + (l15 >> 3)) ^ (lrow & 7);
                    epi[(lrow * 128 + (slt << 4) + ((l15 & 7) << 1)) >> 1] = (bf16)v;
                }
            }
        }
        // own-region readback: same-wave LDS ordering + compiler lgkm waits
        #pragma unroll
        for (int it = 0; it < 16; ++it) {
            int lrow = it * 8 + (lane >> 3);
            int cb   = lane & 7;
            v8bf vv = *(const v8bf*)&epi[(lrow * 128 + ((cb ^ (lrow & 7)) << 4)) >> 1];
            int grow = row0 + wr * 128 + lrow;
            int gcol = col0 + wc * 64 + cb * 8;
            if (gcol < Nstore)
                *(v8bf*)&C[(size_t)grow * ldc + gcol] = vv;
        }
    } else {
        // fused relation reduce in registers. C/D layout: col=l15, row=quad*4+r.
        const int ccol = col0 + wc * 64 + l15;
        const int bb = (row0 >> 7) + wr;
        #pragma unroll
        for (int j = 0; j < 4; ++j) {
            int col = ccol + j * 16;
            bool real = col < Nreal;
            float bc = (real && bias) ? bias[col] : 0.f;
            float red[9];
            float sc = 0.f;
            #pragma unroll
            for (int i = 0; i < 4; ++i)
                #pragma unroll
                for (int r = 0; r < 4; ++r)
                    sc += fmaxf(acc[i][j][r] + bc, 0.f);
            red[0] = sc;
            #pragma unroll
            for (int a = 0; a < 8; ++a) {
                float s = 0.f;
                if ((quad >> 1) == (a & 1)) {
                    const int i = 4 + (a >> 1);
                    #pragma unroll
                    for (int r = 0; r < 4; ++r)
                        s += fmaxf(acc[i][j][r] + bc, 0.f);
                }
                red[1 + a] = s;
            }
            #pragma unroll
            for (int k = 0; k < 9; ++k) {
                red[k] += __shfl_xor(red[k], 16, 64);
                red[k] += __shfl_xor(red[k], 32, 64);
            }
            if (quad == 0 && col < Nstore) {
                #pragma unroll
                for (int a = 0; a < 8; ++a)
                    C[(size_t)(bb * 8 + a) * ldc + col] = (bf16)(red[0] + red[1 + a]);
            }
        }
    }
#undef STAGE_A
#undef STAGE_B
#undef LDA4
#undef LDB2
#undef MM8
#undef UVLOAD
#undef WRITEA
#undef BAR
#undef PRIO1
#undef PRIO0
}

// ---------------------------------------------------------------------------
__global__ void transpose_cast(const float* __restrict__ W, int ldw,
                               int krows, int ncols,
                               bf16* __restrict__ Bt, int ldb,
                               int nalloc, int kalloc)
{
    __shared__ float t[32][33];
    int kb = blockIdx.x * 32;
    int nb = blockIdx.y * 32;
    int tx = threadIdx.x, ty = threadIdx.y;
    #pragma unroll
    for (int i = 0; i < 4; ++i) {
        int k = kb + ty + i * 8, n = nb + tx;
        t[ty + i * 8][tx] = (k < krows && n < ncols) ? W[(size_t)k * ldw + n] : 0.f;
    }
    __syncthreads();
    #pragma unroll
    for (int i = 0; i < 4; ++i) {
        int n = nb + ty + i * 8, k = kb + tx;
        if (n < nalloc && k < kalloc)
            Bt[(size_t)n * ldb + k] = (bf16)t[tx][ty + i * 8];
    }
}

__global__ void cast_bf16_vec(const float* __restrict__ in, bf16* __restrict__ out, size_t n4)
{
    size_t i = blockIdx.x * (size_t)blockDim.x + threadIdx.x;
    if (i >= n4) return;
    float4 v = ((const float4*)in)[i];
    union { bf16 h[4]; u64 q; } o;
    o.h[0] = (bf16)v.x; o.h[1] = (bf16)v.y; o.h[2] = (bf16)v.z; o.h[3] = (bf16)v.w;
    *(u64*)&out[i * 4] = o.q;
}

__global__ void fout_kernel(const bf16* __restrict__ h, const float* __restrict__ Wf2,
                            const float* __restrict__ bf2, float* __restrict__ fout,
                            int rows, int T, int ldp)
{
    int wid  = (int)((blockIdx.x * (size_t)blockDim.x + threadIdx.x) >> 6);
    int lane = threadIdx.x & 63;
    if (wid >= rows) return;
    const bf16* hr = h + (size_t)wid * ldp;
    float s = 0.f;
    for (int c = lane; c < T; c += 64) s += (float)hr[c] * Wf2[c];
    #pragma unroll
    for (int off = 32; off > 0; off >>= 1) s += __shfl_down(s, off, 64);
    if (lane == 0) fout[wid] = s + bf2[0];
}

__global__ void loss_kernel(const float* __restrict__ fout, const int* __restrict__ labels,
                            float* __restrict__ out)
{
    __shared__ float sl[512];
    __shared__ float sc[512];
    int b = threadIdx.x;
    const float* f = fout + (size_t)b * 8;
    int lab = labels[b];
    float rl = 0.f;
    int best = 0;
    float bv = f[0];
    #pragma unroll
    for (int a = 0; a < 8; ++a) {
        float v = f[a];
        rl += fmaxf(v, 0.f) - v * ((a == lab) ? 1.f : 0.f) + log1pf(expf(-fabsf(v)));
        if (v > bv) { bv = v; best = a; }
    }
    sl[b] = rl;
    sc[b] = (best == lab) ? 1.f : 0.f;
    __syncthreads();
    for (int s = 256; s > 0; s >>= 1) {
        if (b < s) { sl[b] += sl[b + s]; sc[b] += sc[b + s]; }
        __syncthreads();
    }
    if (b == 0) { out[0] = sl[0] / 4096.f; out[1] = sc[0] / 512.f; }
}

// ---------------------------------------------------------------------------
extern "C" void kernel_launch(void* const* d_in, const int* in_sizes, int n_in,
                              void* d_out, int out_size, void* d_ws, size_t ws_size,
                              hipStream_t stream)
{
    (void)in_sizes; (void)n_in; (void)out_size;
    const float* x      = (const float*)d_in[0];
    const float* W_emb  = (const float*)d_in[1];
    const float* b_emb  = (const float*)d_in[2];
    const float* Wg1    = (const float*)d_in[3];
    const float* bg1    = (const float*)d_in[4];
    const float* Wg2    = (const float*)d_in[5];
    const float* bg2    = (const float*)d_in[6];
    const float* Wg3    = (const float*)d_in[7];
    const float* bg3    = (const float*)d_in[8];
    const float* Wf1    = (const float*)d_in[9];
    const float* bf1    = (const float*)d_in[10];
    const float* Wf2    = (const float*)d_in[11];
    const float* bf2    = (const float*)d_in[12];
    const int*   labels = (const int*)d_in[13];

    const int B = 512, S = 16, E = 6400, D = 512, T = 1042;
    const int TP  = 1088;   // padded K/col dim (mult of 64)
    const int NA  = 1152;   // padded Bt rows, 128-tiled kernels (9 * 128)
    const int NAB = 1280;   // padded Bt rows, 256-tiled kernel (5 * 256)

    // one-time: allow 128KB dynamic LDS for both gemm256 instantiations
    static int attr_set = 0;
    if (!attr_set) {
        (void)hipFuncSetAttribute(reinterpret_cast<const void*>(&gemm256<1, 0>),
                                  hipFuncAttributeMaxDynamicSharedMemorySize, 131072);
        (void)hipFuncSetAttribute(reinterpret_cast<const void*>(&gemm256<0, 1>),
                                  hipFuncAttributeMaxDynamicSharedMemorySize, 131072);
        attr_set = 1;
    }

    auto alignup = [](size_t v) { return (v + 255) & ~(size_t)255; };

    size_t fixed = alignup((size_t)B * 8 * 4)
                 + alignup((size_t)D * E * 2)
                 + 2 * alignup((size_t)NA * D * 2)
                 + 2 * alignup((size_t)NAB * TP * 2)
                 + alignup((size_t)NA * TP * 2);

    int Bc = 512;
    for (;;) {
        size_t need = fixed
            + alignup((size_t)Bc * S * E * 2)            // xb
            + alignup((size_t)Bc * S * D * 2)            // emb bf16
            + 2 * alignup((size_t)Bc * S * TP * 2)       // U, V
            + alignup((size_t)Bc * 128 * TP * 2)         // H2 (H1 eliminated)
            + alignup((size_t)Bc * 8 * TP * 2)           // REL
            + alignup((size_t)Bc * 8 * TP * 2);          // HF
        if (need <= ws_size || Bc == 16) break;
        Bc >>= 1;
    }

    char* p = (char*)d_ws;
    auto take = [&](size_t bytes) -> void* {
        char* r = p; p += (bytes + 255) & ~(size_t)255; return r;
    };
    float* fout  = (float*)take((size_t)B * 8 * 4);
    bf16* W_embT = (bf16*)take((size_t)D * E * 2);
    bf16* W1aT   = (bf16*)take((size_t)NA * D * 2);
    bf16* W1bT   = (bf16*)take((size_t)NA * D * 2);
    bf16* Wg2T   = (bf16*)take((size_t)NAB * TP * 2);
    bf16* Wg3T   = (bf16*)take((size_t)NAB * TP * 2);
    bf16* Wf1T   = (bf16*)take((size_t)NA * TP * 2);
    bf16* xb     = (bf16*)take((size_t)Bc * S * E * 2);
    bf16* embB   = (bf16*)take((size_t)Bc * S * D * 2);
    bf16* Ubuf   = (bf16*)take((size_t)Bc * S * TP * 2);
    bf16* Vbuf   = (bf16*)take((size_t)Bc * S * TP * 2);
    bf16* H2     = (bf16*)take((size_t)Bc * 128 * TP * 2);
    bf16* REL    = (bf16*)take((size_t)Bc * 8 * TP * 2);
    bf16* HF     = (bf16*)take((size_t)Bc * 8 * TP * 2);

    dim3 tb(32, 8);
    transpose_cast<<<dim3(E / 32, D / 32), tb, 0, stream>>>(W_emb, D, E, D, W_embT, E, D, E);
    transpose_cast<<<dim3(D / 32, NA / 32), tb, 0, stream>>>(Wg1,                   T, D, T, W1aT, D, NA, D);
    transpose_cast<<<dim3(D / 32, NA / 32), tb, 0, stream>>>(Wg1 + (size_t)521 * T, T, D, T, W1bT, D, NA, D);
    transpose_cast<<<dim3(TP / 32, NAB / 32), tb, 0, stream>>>(Wg2, T, T, T, Wg2T, TP, NAB, TP);
    transpose_cast<<<dim3(TP / 32, NAB / 32), tb, 0, stream>>>(Wg3, T, T, T, Wg3T, TP, NAB, TP);
    transpose_cast<<<dim3(TP / 32, NA / 32), tb, 0, stream>>>(Wf1, T, T, T, Wf1T, TP, NA, TP);

    const int nch = B / Bc;
    for (int ch = 0; ch < nch; ++ch) {
        const int M1t = Bc * S / 128, M3t = Bc * 8 / 128;
        const int M2t6 = Bc * 128 / 256;   // 256-row tiles for the big GEMMs

        size_t nx4 = (size_t)Bc * S * E / 4;
        cast_bf16_vec<<<(int)((nx4 + 255) / 256), 256, 0, stream>>>(
            x + (size_t)ch * Bc * S * E, xb, nx4);

        // emb = bf16(x) @ W_emb + b_emb -> bf16 (ld 512)
        gemm_bf16<<<M1t * (D / 128), 256, 0, stream>>>(
            xb, E, W_embT, E, embB, D, M1t, D / 128, D, D, E, b_emb, nullptr, 0, 0, 0);

        // U = emb @ Wg1[0:512] + tag + bg1 -> bf16
        gemm_bf16<<<M1t * (NA / 128), 256, 0, stream>>>(
            embB, D, W1aT, D, Ubuf, TP, M1t, NA / 128, T, TP, D, bg1, Wg1 + (size_t)512 * T, T, 0, 0);
        // V = emb @ Wg1[521:1033] + tag -> bf16
        gemm_bf16<<<M1t * (NA / 128), 256, 0, stream>>>(
            embB, D, W1bT, D, Vbuf, TP, M1t, NA / 128, T, TP, D, nullptr, Wg1 + (size_t)1033 * T, T, 0, 0);

        // H2 = relu(pair_build(U,V) @ Wg2 + bg2)  [fused A-build, 256^2]
        gemm256<1, 0><<<M2t6 * (NAB / 256), 512, 131072, stream>>>(
            nullptr, 0, Ubuf, Vbuf, TP, Wg2T, TP, H2, TP, M2t6, NAB / 256, T, TP, TP, bg2);
        // REL = fused reduce of relu(H2 @ Wg3 + bg3)  [256^2, mode 1]
        gemm256<0, 1><<<M2t6 * (NAB / 256), 512, 131072, stream>>>(
            H2, TP, nullptr, nullptr, 0, Wg3T, TP, REL, TP, M2t6, NAB / 256, T, TP, TP, bg3);

        // HF = relu(REL @ Wf1 + bf1) -> bf16
        gemm_bf16<<<M3t * (NA / 128), 256, 0, stream>>>(
            REL, TP, Wf1T, TP, HF, TP, M3t, NA / 128, T, TP, TP, bf1, nullptr, 0, 1, 0);

        fout_kernel<<<(Bc * 8 * 64 + 255) / 256, 256, 0, stream>>>(
            HF, Wf2, bf2, fout + (size_t)ch * Bc * 8, Bc * 8, T, TP);
    }

    loss_kernel<<<1, 512, 0, stream>>>(fout, labels, (float*)d_out);
}

// Round 6
// 1034.868 us; speedup vs baseline: 1.1291x; 1.1291x over previous
//
#include <hip/hip_runtime.h>
#include <hip/hip_bf16.h>
#include <math.h>

// WReN forward (loss, acc) — bf16 MFMA.
// Round 9: the round-7 source failed twice at container level. To isolate,
// this round = round-7 MINUS gemm_a32 (the only genuinely new kernel body);
// emb path reverts to round-3-verified cast_bf16_vec + gemm_bf16. Kept:
//  - gemm256: round-1 verified K-loop + LDS-routed mode-0 epilogue
//    (HW-verified in rounds 2-3; WRITE 230->165MB expected).
//  - U|V fused into ONE gemm_bf16 dispatch via concat(W1aT,W1bT) +
//    TAG[9][2304] (bg1 folded); pair_build reads the fused UV buffer.
// If this fails at container level too => conclusively infra.

typedef __bf16 bf16;
typedef __bf16 v8bf __attribute__((ext_vector_type(8)));
typedef float  v4f  __attribute__((ext_vector_type(4)));
typedef unsigned long long u64;

#define GAS(p) ((const __attribute__((address_space(1))) void*)(p))
#define LAS(p) ((__attribute__((address_space(3))) void*)(p))

// ---------------------------------------------------------------------------
// 128^2 kernel (unchanged, verified): used for emb, U|V fused, HF.
__global__ __launch_bounds__(256) void gemm_bf16(
    const bf16* __restrict__ A, int lda,
    const bf16* __restrict__ Bt, int ldb,
    bf16* __restrict__ C, int ldc,
    int Mt, int Nt,
    int Nreal, int Nstore, int K,
    const float* __restrict__ bias,
    const float* __restrict__ tagW, int tag_ld,
    int relu, int mode)
{
    __shared__ bf16 As[128 * 32];
    __shared__ bf16 Bs[128 * 32];
    __shared__ bf16 Epi[64 * 132];

    const int L    = blockIdx.x;
    const int xcd  = L & 7;
    const int idx  = L >> 3;
    const int mlee = idx / Nt;
    const int n    = idx - mlee * Nt;
    const int m    = xcd * (Mt >> 3) + mlee;
    const int row0 = m * 128;
    const int col0 = n * 128;

    const int tid  = threadIdx.x;
    const int wv   = tid >> 6;
    const int lane = tid & 63;
    const int quad = lane >> 4;
    const int l15  = lane & 15;
    const int wm0  = (wv >> 1) * 64;
    const int wn0  = (wv & 1) * 64;

    v4f acc[4][4] = {};

    const int srow  = wv * 32 + (lane >> 2);
    const int skoff = (lane & 3) * 8;
    const bf16* ga = A  + (size_t)(row0 + srow) * lda + skoff;
    const bf16* gb = Bt + (size_t)(col0 + srow) * ldb + skoff;
    bf16* laA = &As[(wv * 32) * 32];
    bf16* laB = &Bs[(wv * 32) * 32];

    for (int k0 = 0; k0 < K; k0 += 32) {
        __builtin_amdgcn_global_load_lds(GAS(ga),                    LAS(laA),           16, 0, 0);
        __builtin_amdgcn_global_load_lds(GAS(ga + (size_t)16 * lda), LAS(laA + 16 * 32), 16, 0, 0);
        __builtin_amdgcn_global_load_lds(GAS(gb),                    LAS(laB),           16, 0, 0);
        __builtin_amdgcn_global_load_lds(GAS(gb + (size_t)16 * ldb), LAS(laB + 16 * 32), 16, 0, 0);
        ga += 32; gb += 32;
        __syncthreads();

        v8bf af[4], bfq[4];
        #pragma unroll
        for (int i = 0; i < 4; ++i)
            af[i] = *(const v8bf*)&As[(wm0 + i * 16 + l15) * 32 + quad * 8];
        #pragma unroll
        for (int j = 0; j < 4; ++j)
            bfq[j] = *(const v8bf*)&Bs[(wn0 + j * 16 + l15) * 32 + quad * 8];
        #pragma unroll
        for (int i = 0; i < 4; ++i)
            #pragma unroll
            for (int j = 0; j < 4; ++j)
                acc[i][j] = __builtin_amdgcn_mfma_f32_16x16x32_bf16(af[i], bfq[j], acc[i][j], 0, 0, 0);
        __syncthreads();
    }

    float bcol[4];
    #pragma unroll
    for (int j = 0; j < 4; ++j) {
        int col = col0 + wn0 + j * 16 + l15;
        bcol[j] = (col < Nreal && bias) ? bias[col] : 0.f;
    }

    float s_ctx = 0.f;

    #pragma unroll
    for (int pass = 0; pass < 2; ++pass) {
        if (wm0 == pass * 64) {
            #pragma unroll
            for (int i = 0; i < 4; ++i) {
                #pragma unroll
                for (int j = 0; j < 4; ++j) {
                    #pragma unroll
                    for (int r = 0; r < 4; ++r) {
                        int lrow = i * 16 + quad * 4 + r;
                        int lcol = wn0 + j * 16 + l15;
                        int col  = col0 + lcol;
                        float v = 0.f;
                        if (col < Nreal) {
                            v = acc[i][j][r] + bcol[j];
                            if (tagW) {
                                int row = row0 + pass * 64 + lrow;
                                int tp = row & 15; if (tp > 8) tp = 8;
                                v += tagW[(size_t)tp * tag_ld + col];
                            }
                            if (relu) v = fmaxf(v, 0.f);
                        }
                        Epi[lrow * 132 + lcol] = (bf16)v;
                    }
                }
            }
        }
        __syncthreads();

        if (mode == 0) {
            int lrow = tid >> 2;
            int cg   = (tid & 3) * 32;
            int grow = row0 + pass * 64 + lrow;
            #pragma unroll
            for (int k = 0; k < 4; ++k) {
                int c = cg + k * 8;
                int gcol = col0 + c;
                if (gcol < Nstore) {
                    u64 q0 = *(const u64*)&Epi[lrow * 132 + c];
                    u64 q1 = *(const u64*)&Epi[lrow * 132 + c + 4];
                    uint4 st;
                    st.x = (unsigned)q0; st.y = (unsigned)(q0 >> 32);
                    st.z = (unsigned)q1; st.w = (unsigned)(q1 >> 32);
                    *(uint4*)&C[(size_t)grow * ldc + gcol] = st;
                }
            }
        } else {
            if (tid < 128) {
                int col = tid;
                if (pass == 0) {
                    float s = 0.f;
                    for (int r = 0; r < 64; ++r) s += (float)Epi[r * 132 + col];
                    s_ctx = s;
                } else {
                    float sA[8] = {};
                    for (int r = 0; r < 64; ++r) sA[r >> 3] += (float)Epi[r * 132 + col];
                    int gcol = col0 + col;
                    if (gcol < Nstore) {
                        #pragma unroll
                        for (int a = 0; a < 8; ++a)
                            C[(size_t)(m * 8 + a) * ldc + gcol] = (bf16)(s_ctx + sA[a]);
                    }
                }
            }
        }
        __syncthreads();
    }
}

// ---------------------------------------------------------------------------
// 256x256 tile, BK=64, 8 waves (2M x 4N), 8-phase, dbuf 128KiB LDS.
// K-loop/prologue/gates are the round-1 verified version VERBATIM (215us,
// MfmaUtil 36.5%, bank-conflict 0). Mode-0 epilogue is the LDS-routed
// 16B-store version (HW-verified rounds 2-3; post-loop only).
__global__ __launch_bounds__(512, 2) void gemm256(
    const bf16* __restrict__ A, int lda,
    const bf16* __restrict__ Bt, int ldb,
    bf16* __restrict__ C, int ldc,
    int Mt, int Nt, int Nreal, int Nstore, int K,
    const float* __restrict__ bias, int relu, int mode)
{
    extern __shared__ char smem[];   // [A: 2buf x 2half x 16KB][B: same] = 128KB
    (void)relu;

    const int NTK = K >> 6;

    const int L    = blockIdx.x;
    const int xcd  = L & 7;
    const int idx  = L >> 3;
    const int mlee = idx / Nt;
    const int n    = idx - mlee * Nt;
    const int m    = xcd * (Mt >> 3) + mlee;
    const int row0 = m * 256;
    const int col0 = n * 256;

    const int tid  = threadIdx.x;
    const int wv   = tid >> 6;
    const int lane = tid & 63;
    const int wr   = wv >> 2;          // 2 M-halves
    const int wc   = wv & 3;           // 4 N-quarters
    const int l15  = lane & 15;
    const int quad = lane >> 4;
    const int s7   = l15 & 7;
    const int slot0 = ((0 + quad) ^ s7) << 4;   // kk=0 16B slot (swizzled)
    const int slot1 = ((4 + quad) ^ s7) << 4;   // kk=1

    char* const aB0 = smem + wr * 16384;                                 // +buf*32768
    char* const bB0 = smem + 65536 + (wc >> 1) * 16384 + (wc & 1) * 8192;

    const int srow = tid >> 3;
    const int gce  = ((tid ^ srow) & 7) * 8;
    const bf16* const Ab = A  + (size_t)(row0 + srow) * lda + gce;
    const bf16* const Bb = Bt + (size_t)(col0 + srow) * ldb + gce;
    char* const ldsA = smem + wv * 1024;
    char* const ldsB = smem + 65536 + wv * 1024;

#define STAGE_A(kt, h, buf) { \
    const bf16* s0_ = Ab + (size_t)((h) * 128) * lda + (kt) * 64; \
    char* d_ = ldsA + (buf) * 32768 + (h) * 16384; \
    __builtin_amdgcn_global_load_lds(GAS(s0_),                    LAS(d_),        16, 0, 0); \
    __builtin_amdgcn_global_load_lds(GAS(s0_ + (size_t)64 * lda), LAS(d_ + 8192), 16, 0, 0); }
#define STAGE_B(kt, h, buf) { \
    const bf16* s0_ = Bb + (size_t)((h) * 128) * ldb + (kt) * 64; \
    char* d_ = ldsB + (buf) * 32768 + (h) * 16384; \
    __builtin_amdgcn_global_load_lds(GAS(s0_),                    LAS(d_),        16, 0, 0); \
    __builtin_amdgcn_global_load_lds(GAS(s0_ + (size_t)64 * ldb), LAS(d_ + 8192), 16, 0, 0); }

#define LDA4(buf, qmB) \
    _Pragma("unroll") \
    for (int i_ = 0; i_ < 4; ++i_) { \
        afr[i_][0] = *(const v8bf*)(aB0 + (buf) * 32768 + (((qmB) + i_) * 16 + l15) * 128 + slot0); \
        afr[i_][1] = *(const v8bf*)(aB0 + (buf) * 32768 + (((qmB) + i_) * 16 + l15) * 128 + slot1); \
    }
#define LDB2(buf, nfB) \
    _Pragma("unroll") \
    for (int j_ = 0; j_ < 2; ++j_) { \
        bfr[j_][0] = *(const v8bf*)(bB0 + (buf) * 32768 + (((nfB) + j_) * 16 + l15) * 128 + slot0); \
        bfr[j_][1] = *(const v8bf*)(bB0 + (buf) * 32768 + (((nfB) + j_) * 16 + l15) * 128 + slot1); \
    }
#define MM8(qmB, nfB) \
    _Pragma("unroll") \
    for (int i_ = 0; i_ < 4; ++i_) \
        _Pragma("unroll") \
        for (int j_ = 0; j_ < 2; ++j_) { \
            acc[(qmB) + i_][(nfB) + j_] = __builtin_amdgcn_mfma_f32_16x16x32_bf16(afr[i_][0], bfr[j_][0], acc[(qmB) + i_][(nfB) + j_], 0, 0, 0); \
            acc[(qmB) + i_][(nfB) + j_] = __builtin_amdgcn_mfma_f32_16x16x32_bf16(afr[i_][1], bfr[j_][1], acc[(qmB) + i_][(nfB) + j_], 0, 0, 0); \
        }
#define BAR()   asm volatile("s_barrier" ::: "memory")
#define PRIO1() __builtin_amdgcn_s_setprio(1)
#define PRIO0() __builtin_amdgcn_s_setprio(0)

    v4f acc[8][4] = {};
    v8bf afr[4][2], bfr[2][2];

    // ---- prologue: tile0 (4 halves) + Ah0(1); leave Ah0(1) in flight ----
    STAGE_A(0, 0, 0); STAGE_A(0, 1, 0); STAGE_B(0, 0, 0); STAGE_B(0, 1, 0);
    if (NTK > 1) {
        STAGE_A(1, 0, 1);
        asm volatile("s_waitcnt vmcnt(2)" ::: "memory");
    } else {
        asm volatile("s_waitcnt vmcnt(0)" ::: "memory");
    }
    BAR();

    int t = 0;
    for (; t + 1 < NTK; t += 2) {
        // P1: tile t, A qm0 + B nf01
        LDA4(0, 0); LDB2(0, 0); STAGE_A(t + 1, 1, 1);
        BAR(); PRIO1(); MM8(0, 0); PRIO0(); BAR();
        // P2: B nf23 (A regs reused)
        LDB2(0, 2); STAGE_B(t + 1, 0, 1);
        BAR(); PRIO1(); MM8(0, 2); PRIO0(); BAR();
        // P3: A qm1 + B nf01
        LDA4(0, 4); LDB2(0, 0); STAGE_B(t + 1, 1, 1);
        BAR(); PRIO1(); MM8(4, 0); PRIO0(); BAR();
        // P4: B nf23 ; gate for tile t+1
        LDB2(0, 2);
        if (t + 2 < NTK) STAGE_A(t + 2, 0, 0);
        BAR(); PRIO1(); MM8(4, 2); PRIO0();
        if (t + 2 < NTK) asm volatile("s_waitcnt vmcnt(2)" ::: "memory");
        else             asm volatile("s_waitcnt vmcnt(0)" ::: "memory");
        BAR();
        // P5: tile t+1
        LDA4(1, 0); LDB2(1, 0);
        if (t + 2 < NTK) STAGE_A(t + 2, 1, 0);
        BAR(); PRIO1(); MM8(0, 0); PRIO0(); BAR();
        // P6
        LDB2(1, 2);
        if (t + 2 < NTK) STAGE_B(t + 2, 0, 0);
        BAR(); PRIO1(); MM8(0, 2); PRIO0(); BAR();
        // P7
        LDA4(1, 4); LDB2(1, 0);
        if (t + 2 < NTK) STAGE_B(t + 2, 1, 0);
        BAR(); PRIO1(); MM8(4, 0); PRIO0(); BAR();
        // P8 ; gate for tile t+2
        LDB2(1, 2);
        if (t + 3 < NTK) STAGE_A(t + 3, 0, 1);
        BAR(); PRIO1(); MM8(4, 2); PRIO0();
        if (t + 3 < NTK) asm volatile("s_waitcnt vmcnt(2)" ::: "memory");
        else             asm volatile("s_waitcnt vmcnt(0)" ::: "memory");
        BAR();
    }
    if (t < NTK) {  // peeled odd tile (buf0), no stages
        LDA4(0, 0); LDB2(0, 0); BAR(); PRIO1(); MM8(0, 0); PRIO0(); BAR();
        LDB2(0, 2);             BAR(); PRIO1(); MM8(0, 2); PRIO0(); BAR();
        LDA4(0, 4); LDB2(0, 0); BAR(); PRIO1(); MM8(4, 0); PRIO0(); BAR();
        LDB2(0, 2);             BAR(); PRIO1(); MM8(4, 2); PRIO0();
    }

    // ---- epilogue ----
    // C/D layout: col = l15, row = quad*4 + r  [m89/m91-verified]
    const int ccol = col0 + wc * 64 + l15;

    if (mode == 0) {
        // LDS re-stage (bank-swizzled, K-loop LDS now dead), 16B stores.
        __syncthreads();
        bf16* epi = (bf16*)(smem + wv * 16384);   // this wave's 128x64 tile
        #pragma unroll
        for (int j = 0; j < 4; ++j) {
            int col = ccol + j * 16;
            bool real = col < Nreal;
            float bc = (real && bias) ? bias[col] : 0.f;
            #pragma unroll
            for (int i = 0; i < 8; ++i) {
                #pragma unroll
                for (int r = 0; r < 4; ++r) {
                    int lrow = i * 16 + quad * 4 + r;
                    float v = real ? fmaxf(acc[i][j][r] + bc, 0.f) : 0.f;
                    int slt = (j * 2 + (l15 >> 3)) ^ (lrow & 7);
                    epi[(lrow * 128 + (slt << 4) + ((l15 & 7) << 1)) >> 1] = (bf16)v;
                }
            }
        }
        // own-region readback: same-wave LDS ordering + compiler lgkm waits
        #pragma unroll
        for (int it = 0; it < 16; ++it) {
            int lrow = it * 8 + (lane >> 3);
            int cb   = lane & 7;
            v8bf vv = *(const v8bf*)&epi[(lrow * 128 + ((cb ^ (lrow & 7)) << 4)) >> 1];
            int grow = row0 + wr * 128 + lrow;
            int gcol = col0 + wc * 64 + cb * 8;
            if (gcol < Nstore)
                *(v8bf*)&C[(size_t)grow * ldc + gcol] = vv;
        }
    } else {
        // fused relation reduce in registers (round-1 verbatim).
        const int bb = (row0 >> 7) + wr;
        #pragma unroll
        for (int j = 0; j < 4; ++j) {
            int col = ccol + j * 16;
            bool real = col < Nreal;
            float bc = (real && bias) ? bias[col] : 0.f;
            float red[9];
            float sc = 0.f;
            #pragma unroll
            for (int i = 0; i < 4; ++i)
                #pragma unroll
                for (int r = 0; r < 4; ++r)
                    sc += fmaxf(acc[i][j][r] + bc, 0.f);
            red[0] = sc;
            #pragma unroll
            for (int a = 0; a < 8; ++a) {
                float s = 0.f;
                if ((quad >> 1) == (a & 1)) {
                    const int i = 4 + (a >> 1);
                    #pragma unroll
                    for (int r = 0; r < 4; ++r)
                        s += fmaxf(acc[i][j][r] + bc, 0.f);
                }
                red[1 + a] = s;
            }
            #pragma unroll
            for (int k = 0; k < 9; ++k) {
                red[k] += __shfl_xor(red[k], 16, 64);
                red[k] += __shfl_xor(red[k], 32, 64);
            }
            if (quad == 0 && col < Nstore) {
                #pragma unroll
                for (int a = 0; a < 8; ++a)
                    C[(size_t)(bb * 8 + a) * ldc + col] = (bf16)(red[0] + red[1 + a]);
            }
        }
    }
#undef STAGE_A
#undef STAGE_B
#undef LDA4
#undef LDB2
#undef MM8
#undef BAR
#undef PRIO1
#undef PRIO0
}

// ---------------------------------------------------------------------------
__global__ void transpose_cast(const float* __restrict__ W, int ldw,
                               int krows, int ncols,
                               bf16* __restrict__ Bt, int ldb,
                               int nalloc, int kalloc)
{
    __shared__ float t[32][33];
    int kb = blockIdx.x * 32;
    int nb = blockIdx.y * 32;
    int tx = threadIdx.x, ty = threadIdx.y;
    #pragma unroll
    for (int i = 0; i < 4; ++i) {
        int k = kb + ty + i * 8, n = nb + tx;
        t[ty + i * 8][tx] = (k < krows && n < ncols) ? W[(size_t)k * ldw + n] : 0.f;
    }
    __syncthreads();
    #pragma unroll
    for (int i = 0; i < 4; ++i) {
        int n = nb + ty + i * 8, k = kb + tx;
        if (n < nalloc && k < kalloc)
            Bt[(size_t)n * ldb + k] = (bf16)t[tx][ty + i * 8];
    }
}

__global__ void cast_bf16_vec(const float* __restrict__ in, bf16* __restrict__ out, size_t n4)
{
    size_t i = blockIdx.x * (size_t)blockDim.x + threadIdx.x;
    if (i >= n4) return;
    float4 v = ((const float4*)in)[i];
    union { bf16 h[4]; u64 q; } o;
    o.h[0] = (bf16)v.x; o.h[1] = (bf16)v.y; o.h[2] = (bf16)v.z; o.h[3] = (bf16)v.w;
    *(u64*)&out[i * 4] = o.q;
}

// TAG[tp][c] table for the fused U|V GEMM. c<half: U-part tag + bg1 folded;
// c>=half: V-part tag. Pad columns -> 0.
__global__ void build_tag(const float* __restrict__ Wg1, const float* __restrict__ bg1,
                          float* __restrict__ TAG, int T, int D, int half, int W)
{
    int i = blockIdx.x * blockDim.x + threadIdx.x;
    if (i >= 9 * W) return;
    int tp = i / W, c = i % W;
    float v = 0.f;
    if (c < half) {
        if (c < T) v = Wg1[(size_t)(D + tp) * T + c] + bg1[c];
    } else {
        int cc = c - half;
        if (cc < T) v = Wg1[(size_t)(2 * D + 9 + tp) * T + cc];
    }
    TAG[i] = v;
}

// H1[r, :] = bf16(relu(U[bb*16+(p&7)] + V[bb*16+(p>>3)])), r = bb*128+p.
// U = UV[:, 0:half), V = UV[:, half:).
__global__ void pair_build(const bf16* __restrict__ UV, int lduv, int voff,
                           bf16* __restrict__ H1, int ldp)
{
    int r = blockIdx.x;
    int p = r & 127, bb = r >> 7;
    const bf16* ur = UV + (size_t)(bb * 16 + (p & 7)) * lduv;
    const bf16* vr = UV + (size_t)(bb * 16 + (p >> 3)) * lduv + voff;
    bf16* hr = H1 + (size_t)r * ldp;
    int nch = ldp >> 3;
    for (int c8 = threadIdx.x; c8 < nch; c8 += blockDim.x) {
        v8bf u = *(const v8bf*)&ur[c8 * 8];
        v8bf v = *(const v8bf*)&vr[c8 * 8];
        v8bf o;
        #pragma unroll
        for (int i = 0; i < 8; ++i)
            o[i] = (bf16)fmaxf((float)u[i] + (float)v[i], 0.f);
        *(v8bf*)&hr[c8 * 8] = o;
    }
}

__global__ void fout_kernel(const bf16* __restrict__ h, const float* __restrict__ Wf2,
                            const float* __restrict__ bf2, float* __restrict__ fout,
                            int rows, int T, int ldp)
{
    int wid  = (int)((blockIdx.x * (size_t)blockDim.x + threadIdx.x) >> 6);
    int lane = threadIdx.x & 63;
    if (wid >= rows) return;
    const bf16* hr = h + (size_t)wid * ldp;
    float s = 0.f;
    for (int c = lane; c < T; c += 64) s += (float)hr[c] * Wf2[c];
    #pragma unroll
    for (int off = 32; off > 0; off >>= 1) s += __shfl_down(s, off, 64);
    if (lane == 0) fout[wid] = s + bf2[0];
}

__global__ void loss_kernel(const float* __restrict__ fout, const int* __restrict__ labels,
                            float* __restrict__ out)
{
    __shared__ float sl[512];
    __shared__ float sc[512];
    int b = threadIdx.x;
    const float* f = fout + (size_t)b * 8;
    int lab = labels[b];
    float rl = 0.f;
    int best = 0;
    float bv = f[0];
    #pragma unroll
    for (int a = 0; a < 8; ++a) {
        float v = f[a];
        rl += fmaxf(v, 0.f) - v * ((a == lab) ? 1.f : 0.f) + log1pf(expf(-fabsf(v)));
        if (v > bv) { bv = v; best = a; }
    }
    sl[b] = rl;
    sc[b] = (best == lab) ? 1.f : 0.f;
    __syncthreads();
    for (int s = 256; s > 0; s >>= 1) {
        if (b < s) { sl[b] += sl[b + s]; sc[b] += sc[b + s]; }
        __syncthreads();
    }
    if (b == 0) { out[0] = sl[0] / 4096.f; out[1] = sc[0] / 512.f; }
}

// ---------------------------------------------------------------------------
extern "C" void kernel_launch(void* const* d_in, const int* in_sizes, int n_in,
                              void* d_out, int out_size, void* d_ws, size_t ws_size,
                              hipStream_t stream)
{
    (void)in_sizes; (void)n_in; (void)out_size;
    const float* x      = (const float*)d_in[0];
    const float* W_emb  = (const float*)d_in[1];
    const float* b_emb  = (const float*)d_in[2];
    const float* Wg1    = (const float*)d_in[3];
    const float* bg1    = (const float*)d_in[4];
    const float* Wg2    = (const float*)d_in[5];
    const float* bg2    = (const float*)d_in[6];
    const float* Wg3    = (const float*)d_in[7];
    const float* bg3    = (const float*)d_in[8];
    const float* Wf1    = (const float*)d_in[9];
    const float* bf1    = (const float*)d_in[10];
    const float* Wf2    = (const float*)d_in[11];
    const float* bf2    = (const float*)d_in[12];
    const int*   labels = (const int*)d_in[13];

    const int B = 512, S = 16, E = 6400, D = 512, T = 1042;
    const int TP  = 1088;   // padded K/col dim (mult of 64)
    const int NA  = 1152;   // padded Bt rows, 128-tiled kernels (9 * 128)
    const int NAB = 1280;   // padded Bt rows, 256-tiled kernel (5 * 256)
    const int NA2 = 2304;   // fused U|V width (2 * NA)

    static int attr_set = 0;
    if (!attr_set) {
        (void)hipFuncSetAttribute(reinterpret_cast<const void*>(&gemm256),
                                  hipFuncAttributeMaxDynamicSharedMemorySize, 131072);
        attr_set = 1;
    }

    auto alignup = [](size_t v) { return (v + 255) & ~(size_t)255; };

    size_t fixed = alignup((size_t)B * 8 * 4)
                 + alignup((size_t)D * E * 2)
                 + alignup((size_t)NA2 * D * 2)
                 + 2 * alignup((size_t)NAB * TP * 2)
                 + alignup((size_t)NA * TP * 2)
                 + alignup((size_t)9 * NA2 * 4);

    int Bc = 512;
    for (;;) {
        size_t need = fixed
            + alignup((size_t)Bc * S * E * 2)            // xb
            + alignup((size_t)Bc * S * D * 2)            // emb bf16
            + alignup((size_t)Bc * S * NA2 * 2)          // UV fused
            + 2 * alignup((size_t)Bc * 128 * TP * 2)     // H1, H2
            + alignup((size_t)Bc * 8 * TP * 2)           // REL
            + alignup((size_t)Bc * 8 * TP * 2);          // HF
        if (need <= ws_size || Bc == 16) break;
        Bc >>= 1;
    }

    char* p = (char*)d_ws;
    auto take = [&](size_t bytes) -> void* {
        char* r = p; p += (bytes + 255) & ~(size_t)255; return r;
    };
    float* fout  = (float*)take((size_t)B * 8 * 4);
    bf16* W_embT = (bf16*)take((size_t)D * E * 2);
    bf16* W1abT  = (bf16*)take((size_t)NA2 * D * 2);
    bf16* Wg2T   = (bf16*)take((size_t)NAB * TP * 2);
    bf16* Wg3T   = (bf16*)take((size_t)NAB * TP * 2);
    bf16* Wf1T   = (bf16*)take((size_t)NA * TP * 2);
    float* TAG   = (float*)take((size_t)9 * NA2 * 4);
    bf16* xb     = (bf16*)take((size_t)Bc * S * E * 2);
    bf16* embB   = (bf16*)take((size_t)Bc * S * D * 2);
    bf16* UV     = (bf16*)take((size_t)Bc * S * NA2 * 2);
    bf16* H1     = (bf16*)take((size_t)Bc * 128 * TP * 2);
    bf16* H2     = (bf16*)take((size_t)Bc * 128 * TP * 2);
    bf16* REL    = (bf16*)take((size_t)Bc * 8 * TP * 2);
    bf16* HF     = (bf16*)take((size_t)Bc * 8 * TP * 2);

    dim3 tb(32, 8);
    transpose_cast<<<dim3(E / 32, D / 32), tb, 0, stream>>>(W_emb, D, E, D, W_embT, E, D, E);
    transpose_cast<<<dim3(D / 32, NA / 32), tb, 0, stream>>>(Wg1,                   T, D, T, W1abT, D, NA, D);
    transpose_cast<<<dim3(D / 32, NA / 32), tb, 0, stream>>>(Wg1 + (size_t)521 * T, T, D, T, W1abT + (size_t)NA * D, D, NA, D);
    transpose_cast<<<dim3(TP / 32, NAB / 32), tb, 0, stream>>>(Wg2, T, T, T, Wg2T, TP, NAB, TP);
    transpose_cast<<<dim3(TP / 32, NAB / 32), tb, 0, stream>>>(Wg3, T, T, T, Wg3T, TP, NAB, TP);
    transpose_cast<<<dim3(TP / 32, NA / 32), tb, 0, stream>>>(Wf1, T, T, T, Wf1T, TP, NA, TP);
    build_tag<<<(9 * NA2 + 255) / 256, 256, 0, stream>>>(Wg1, bg1, TAG, T, D, NA, NA2);

    const int nch = B / Bc;
    for (int ch = 0; ch < nch; ++ch) {
        const int M1t = Bc * S / 128, M3t = Bc * 8 / 128;
        const int M2t6 = Bc * 128 / 256;   // 256-row tiles for the big GEMMs

        size_t nx4 = (size_t)Bc * S * E / 4;
        cast_bf16_vec<<<(int)((nx4 + 255) / 256), 256, 0, stream>>>(
            x + (size_t)ch * Bc * S * E, xb, nx4);

        // emb = bf16(x) @ W_emb + b_emb -> bf16 (ld 512)
        gemm_bf16<<<M1t * (D / 128), 256, 0, stream>>>(
            xb, E, W_embT, E, embB, D, M1t, D / 128, D, D, E, b_emb, nullptr, 0, 0, 0);

        // UV = emb @ [W1a | W1b] + TAG (bias folded) -> bf16, one dispatch
        gemm_bf16<<<M1t * (NA2 / 128), 256, 0, stream>>>(
            embB, D, W1abT, D, UV, NA2, M1t, NA2 / 128, NA2, NA2, D,
            nullptr, TAG, NA2, 0, 0);

        pair_build<<<Bc * 128, 128, 0, stream>>>(UV, NA2, NA, H1, TP);

        // H2 = relu(H1 @ Wg2 + bg2) -> bf16   [256^2 8-phase, round-1 loop]
        gemm256<<<M2t6 * (NAB / 256), 512, 131072, stream>>>(
            H1, TP, Wg2T, TP, H2, TP, M2t6, NAB / 256, T, TP, TP, bg2, 1, 0);
        // REL = fused reduce of relu(H2 @ Wg3 + bg3)   [mode 1]
        gemm256<<<M2t6 * (NAB / 256), 512, 131072, stream>>>(
            H2, TP, Wg3T, TP, REL, TP, M2t6, NAB / 256, T, TP, TP, bg3, 1, 1);

        // HF = relu(REL @ Wf1 + bf1) -> bf16
        gemm_bf16<<<M3t * (NA / 128), 256, 0, stream>>>(
            REL, TP, Wf1T, TP, HF, TP, M3t, NA / 128, T, TP, TP, bf1, nullptr, 0, 1, 0);

        fout_kernel<<<(Bc * 8 * 64 + 255) / 256, 256, 0, stream>>>(
            HF, Wf2, bf2, fout + (size_t)ch * Bc * 8, Bc * 8, T, TP);
    }

    loss_kernel<<<1, 512, 0, stream>>>(fout, labels, (float*)d_out);
}